// Round 7
// baseline (133.009 us; speedup 1.0000x reference)
//
#include <hip/hip_runtime.h>
#include <hip/hip_bf16.h>

#define SEQ 394
#define EMB 300
#define EMBP 312                          // 624B rows: 16B-aligned, odd granule stride
#define NROWS (64 * SEQ)                  // 25216
#define XPTOT ((long)NROWS * EMBP)        // 7,867,392 elems
#define NCHT 118                          // chunks of 32: 30 (br0) + 39 (br1) + 49 (br2)
#define CBE0 29                           // last chunk of br0 (odd)
#define CBE1 68                           // last chunk of br1 (even)
#define XELEM 45056                       // 5632 granules = 11 rounds x 512 threads, covers max addr 41191

typedef __attribute__((ext_vector_type(8))) short short8;
typedef __attribute__((ext_vector_type(16))) float f32x16;

__device__ __forceinline__ unsigned short f2b(float f) {
    unsigned u = __float_as_uint(f);
    u += 0x7FFFu + ((u >> 16) & 1u);   // RNE to bf16
    return (unsigned short)(u >> 16);
}

__device__ __forceinline__ void gload_lds16(const void* g, void* l) {
    __builtin_amdgcn_global_load_lds(
        (const __attribute__((address_space(1))) void*)g,
        (__attribute__((address_space(3))) void*)l, 16, 0, 0);
}

// ---------------- pack kernels ----------------

// x fp32 [25216][300] -> xp bf16 [25216][312], cols 300..311 zero
__global__ __launch_bounds__(256)
void pack_x_kernel(const float* __restrict__ x, unsigned short* __restrict__ xp)
{
    long q = (long)blockIdx.x * 256 + threadIdx.x;       // quad of 4 elems; 1,966,848 exact
    int row = (int)(q / 78);
    int c4  = ((int)(q - (long)row * 78)) * 4;
    ushort4 u;
    if (c4 < 300) {
        float4 v = *(const float4*)(x + (long)row * 300 + c4);
        u = make_ushort4(f2b(v.x), f2b(v.y), f2b(v.z), f2b(v.w));
    } else {
        u = make_ushort4(0, 0, 0, 0);
    }
    *(ushort4*)(xp + q * 4) = u;
}

// W -> A-fragment-ordered blob: granule G = ((c*8 + g)*2 + ks)*64 + lane holds
// W[f = g*32 + (lane&31)][k = kof(c) + ks*16 + (lane>>5)*8 + j] over the 312-padded
// k-axis (zero where r>=n or e>=300). A wave MFMA-loads its frags as contiguous 1KB.
__global__ __launch_bounds__(256)
void pack_w_kernel(const float* __restrict__ W1, const float* __restrict__ W2,
                   const float* __restrict__ W3, unsigned short* __restrict__ wb)
{
    int G = blockIdx.x * 256 + threadIdx.x;              // 120,832 total (exact)
    int l  = G & 63;
    int ks = (G >> 6) & 1;
    int g  = (G >> 7) & 7;
    int c  = G >> 10;
    const float* Wg; int n, cb;
    if (c <= CBE0)      { Wg = W1; n = 3; cb = 0;        }
    else if (c <= CBE1) { Wg = W2; n = 4; cb = CBE0 + 1; }
    else                { Wg = W3; n = 5; cb = CBE1 + 1; }
    const int K = n * 300;
    const int f = g * 32 + (l & 31);
    const int kl = (c - cb) * 32 + ks * 16 + (l >> 5) * 8;
    unsigned short v[8];
#pragma unroll
    for (int j = 0; j < 8; ++j) {
        int kk = kl + j;
        int r  = kk / EMBP;
        int e  = kk - r * EMBP;
        v[j] = (r < n && e < 300) ? f2b(Wg[(long)f * K + r * 300 + e]) : (unsigned short)0;
    }
    unsigned short* dst = wb + (long)G * 8;
    *(ushort4*)dst       = make_ushort4(v[0], v[1], v[2], v[3]);
    *(ushort4*)(dst + 4) = make_ushort4(v[4], v[5], v[6], v[7]);
}

// ---------------- main kernel ----------------
// Grid 256 = batch(64) x wtile(4: offsets 0/88/176/263, 128 windows each, overlaps
// idempotent under max). 512 thr = 8 waves = 4 fsets x 2 wsets; wave = 64f x 64w
// via mfma_32x32x16. X resident in LDS (only LDS user); W streamed straight into
// registers in fragment order. No barriers after the X fill.

__global__ __launch_bounds__(512, 2)
void convgemm_kernel(const unsigned short* __restrict__ xp,
                     const unsigned short* __restrict__ wb,
                     const float* __restrict__ b1, const float* __restrict__ b2,
                     const float* __restrict__ b3,
                     float* __restrict__ out)
{
    __shared__ unsigned short X[XELEM];                  // 90112 B

    const int tid  = threadIdx.x;
    const int lane = tid & 63;
    const int wid  = tid >> 6;
    const int wfs  = wid >> 1;                           // filter-set 0..3
    const int ws   = wid & 1;                            // window-set 0..1
    const int lm   = lane & 31;
    const int l5   = lane >> 5;
    const int b    = blockIdx.x >> 2;
    const int ti   = blockIdx.x & 3;
    const int woff = (ti == 0) ? 0 : (ti == 1) ? 88 : (ti == 2) ? 176 : 263;

    // ---- prologue: fill resident X (rows woff.., clamped at buffer end) ----
    {
        const long xbase = ((long)b * SEQ + woff) * EMBP;    // granule-aligned (312 = 39*8)
        const long slim  = XPTOT - 8;
#pragma unroll
        for (int rd = 0; rd < 11; ++rd) {
            long se = xbase + (long)(rd * 512 + tid) * 8;
            if (se > slim) se = slim;                        // finite garbage; masked in epilogue
            gload_lds16(xp + se, &X[(rd * 512 + wid * 64) * 8]);
        }
    }
    __syncthreads();

    // ---- W fragment loads (global -> registers, frag-ordered blob) ----
    const unsigned short* wp0 = wb + ((long)(wfs * 2) * 128 + lane) * 8;
    auto LDW = [&](int c, short8 w[2][2]) {
        const short8* p = (const short8*)(wp0 + (long)c * 8192);
        w[0][0] = p[0];   w[0][1] = p[64];                   // mi=0, ks=0/1 (offset imm 0/1024)
        w[1][0] = p[128]; w[1][1] = p[192];                  // mi=1 (offset imm 2048/3072)
    };

    // ---- bx reads: 2 row-base pointers + compile-time offsets ----
    const unsigned short* xr0 = &X[(ws * 64 + lm) * EMBP + l5 * 8];
    const unsigned short* xr1 = xr0 + 32 * EMBP;
    auto RDBX = [&](int ko, short8 bx[2][2]) {               // ko = branch-local elem offset
        bx[0][0] = *(const short8*)(xr0 + ko);
        bx[0][1] = *(const short8*)(xr0 + ko + 16);
        bx[1][0] = *(const short8*)(xr1 + ko);
        bx[1][1] = *(const short8*)(xr1 + ko + 16);
    };

    f32x16 acc[2][2];
#pragma unroll
    for (int i = 0; i < 2; ++i)
#pragma unroll
        for (int j = 0; j < 2; ++j)
            acc[i][j] = (f32x16)0.0f;

    auto MFMA8 = [&](short8 w[2][2], short8 bx[2][2]) {
#pragma unroll
        for (int mi = 0; mi < 2; ++mi)
#pragma unroll
            for (int ni = 0; ni < 2; ++ni) {
                acc[mi][ni] = __builtin_amdgcn_mfma_f32_32x32x16_bf16(w[mi][0], bx[ni][0], acc[mi][ni], 0, 0, 0);
                acc[mi][ni] = __builtin_amdgcn_mfma_f32_32x32x16_bf16(w[mi][1], bx[ni][1], acc[mi][ni], 0, 0, 0);
            }
    };

    auto EPI = [&](int br) {
        const float* bg = (br == 0) ? b1 : (br == 1) ? b2 : b3;
        const int Nw = 391 - br;
        const int ob = b * 768 + br * 256;
#pragma unroll
        for (int mi = 0; mi < 2; ++mi) {
#pragma unroll
            for (int r = 0; r < 16; ++r) {
                const int d = wfs * 64 + mi * 32 + (r & 3) + 8 * (r >> 2) + 4 * l5;  // C/D row map
                const float bv = bg[d];
                float m = 0.f;
#pragma unroll
                for (int ni = 0; ni < 2; ++ni) {
                    int w = woff + ws * 64 + ni * 32 + lm;                           // C/D col map
                    float v = fmaxf(acc[mi][ni][r] + bv, 0.f);
                    if (w >= Nw) v = 0.f;
                    m = fmaxf(m, v);
                }
#pragma unroll
                for (int off = 1; off < 32; off <<= 1)
                    m = fmaxf(m, __shfl_xor(m, off));                                // within 32-half
                if (lm == 0)
                    atomicMax((int*)(out + ob + d), __float_as_int(m));
            }
        }
#pragma unroll
        for (int i = 0; i < 2; ++i)
#pragma unroll
            for (int j = 0; j < 2; ++j)
                acc[i][j] = (f32x16)0.0f;
    };

    short8 wA[2][2], wB[2][2], bxA[2][2], bxB[2][2];
    LDW(0, wA); LDW(1, wB);
    RDBX(0, bxA);

    for (int c = 0; c < NCHT; c += 2) {
        // ---- even body: chunk c (wA, bxA); prefetch bx(c+1), W(c+2) ----
        {
            const int t = c + 1;                              // always <= 117
            const int ko = (t >= 69) ? (t - 69) * 32 : (t >= 30) ? (t - 30) * 32 : t * 32;
            RDBX(ko, bxB);
        }
        MFMA8(wA, bxA);
        if (c + 2 < NCHT) LDW(c + 2, wA);
        if (c == CBE1) EPI(1);                                // 68 even

        // ---- odd body: chunk c+1 (wB, bxB); prefetch bx(c+2), W(c+3) ----
        {
            const int t = c + 2;
            if (t < NCHT) {
                const int ko = (t >= 69) ? (t - 69) * 32 : (t >= 30) ? (t - 30) * 32 : t * 32;
                RDBX(ko, bxA);
            }
        }
        MFMA8(wB, bxB);
        if (c + 3 < NCHT) LDW(c + 3, wB);
        if (c + 1 == CBE0) EPI(0);                            // 29 odd
        if (c + 1 == NCHT - 1) EPI(2);                        // 117 odd
    }
}

// ---------------- fallback (no-workspace path) ----------------

typedef __attribute__((ext_vector_type(4))) float f32x4;

__device__ __forceinline__ void load_chunk(const float* __restrict__ Wg,
                                           const float* __restrict__ xb,
                                           int K, int dbase, int i0, int k0, int tid,
                                           float4 wv[4], float4 xv[4])
{
#pragma unroll
    for (int i = 0; i < 4; ++i) {
        int fi  = tid + (i << 8);
        int row = fi >> 3;
        int c4  = (fi & 7) << 2;
        int col = k0 + c4;
        if (col < K)
            wv[i] = *(const float4*)(Wg + (long)(dbase + row) * K + col);
        else
            wv[i] = make_float4(0.f, 0.f, 0.f, 0.f);
        int off = (i0 + row) * EMB + col;
        int lim = SEQ * EMB - 4;
        if (off > lim) off = lim;
        xv[i] = *(const float4*)(xb + off);
    }
}

__device__ __forceinline__ void write_chunk(unsigned short (*Wb)[40],
                                            unsigned short (*Xb)[40],
                                            int tid, const float4 wv[4], const float4 xv[4])
{
#pragma unroll
    for (int i = 0; i < 4; ++i) {
        int fi  = tid + (i << 8);
        int row = fi >> 3;
        int c4  = (fi & 7) << 2;
        *(ushort4*)&Wb[row][c4] = make_ushort4(f2b(wv[i].x), f2b(wv[i].y), f2b(wv[i].z), f2b(wv[i].w));
        *(ushort4*)&Xb[row][c4] = make_ushort4(f2b(xv[i].x), f2b(xv[i].y), f2b(xv[i].z), f2b(xv[i].w));
    }
}

typedef __attribute__((ext_vector_type(8))) short short8f;

__global__ __launch_bounds__(256, 2)
void convmax_fallback(const float* __restrict__ x,
                      const float* __restrict__ W1, const float* __restrict__ W2,
                      const float* __restrict__ W3,
                      const float* __restrict__ b1, const float* __restrict__ b2,
                      const float* __restrict__ b3,
                      float* __restrict__ out)
{
    const int br = blockIdx.z;
    const int K  = (br == 0) ? 900 : (br == 1) ? 1200 : 1500;
    const int Nw = SEQ - 3 - br;
    const float* Wg = (br == 0) ? W1 : (br == 1) ? W2 : W3;
    const float* bg = (br == 0) ? b1 : (br == 1) ? b2 : b3;
    const int b  = blockIdx.x;
    const int mt = blockIdx.y >> 2;
    const int nt = blockIdx.y & 3;
    const int dbase = mt * 128;
    const int i0    = nt * 128;
    const float* xb = x + b * (SEQ * EMB);
    const int nch = (K + 31) >> 5;

    __shared__ unsigned short Wl[2][128][40];
    __shared__ unsigned short Xl[2][128][40];

    const int tid  = threadIdx.x;
    const int lane = tid & 63;
    const int wid  = tid >> 6;
    const int wr = wid >> 1, wc = wid & 1;
    const int lr = lane & 15, lg = lane >> 4;

    f32x4 acc[4][4];
#pragma unroll
    for (int i = 0; i < 4; ++i)
#pragma unroll
        for (int j = 0; j < 4; ++j)
            acc[i][j] = (f32x4)0.0f;

    {
        float4 wv[4], xv[4];
        load_chunk(Wg, xb, K, dbase, i0, 0, tid, wv, xv);
        write_chunk(Wl[0], Xl[0], tid, wv, xv);
    }
    __syncthreads();

    for (int c = 0; c < nch; ++c) {
        const int cur = c & 1;
        float4 wv[4], xv[4];
        const bool pf = (c + 1 < nch);
        if (pf) load_chunk(Wg, xb, K, dbase, i0, (c + 1) << 5, tid, wv, xv);

        short8f af[4], bfr[4];
#pragma unroll
        for (int mi = 0; mi < 4; ++mi)
            af[mi] = *(const short8f*)&Wl[cur][wr * 64 + mi * 16 + lr][lg * 8];
#pragma unroll
        for (int ni = 0; ni < 4; ++ni)
            bfr[ni] = *(const short8f*)&Xl[cur][wc * 64 + ni * 16 + lr][lg * 8];
#pragma unroll
        for (int mi = 0; mi < 4; ++mi)
#pragma unroll
            for (int ni = 0; ni < 4; ++ni)
                acc[mi][ni] = __builtin_amdgcn_mfma_f32_16x16x32_bf16(af[mi], bfr[ni], acc[mi][ni], 0, 0, 0);

        if (pf) write_chunk(Wl[cur ^ 1], Xl[cur ^ 1], tid, wv, xv);
        __syncthreads();
    }

    const int ob = b * 768 + br * 256;
#pragma unroll
    for (int mi = 0; mi < 4; ++mi) {
#pragma unroll
        for (int rI = 0; rI < 4; ++rI) {
            const int d = dbase + wr * 64 + mi * 16 + lg * 4 + rI;
            const float bv = bg[d];
            float m = 0.f;
#pragma unroll
            for (int ni = 0; ni < 4; ++ni) {
                int win = i0 + wc * 64 + ni * 16 + lr;
                float v = acc[mi][ni][rI] + bv;
                v = fmaxf(v, 0.f);
                if (win >= Nw) v = 0.f;
                m = fmaxf(m, v);
            }
#pragma unroll
            for (int off = 1; off < 16; off <<= 1)
                m = fmaxf(m, __shfl_xor(m, off));
            if (lr == 0)
                atomicMax((int*)(out + ob + d), __float_as_int(m));
        }
    }
}

// ---------------- launch ----------------

extern "C" void kernel_launch(void* const* d_in, const int* in_sizes, int n_in,
                              void* d_out, int out_size, void* d_ws, size_t ws_size,
                              hipStream_t stream) {
    const float* x  = (const float*)d_in[0];
    const float* W1 = (const float*)d_in[1];
    const float* W2 = (const float*)d_in[2];
    const float* W3 = (const float*)d_in[3];
    const float* b1 = (const float*)d_in[4];
    const float* b2 = (const float*)d_in[5];
    const float* b3 = (const float*)d_in[6];
    float* out = (float*)d_out;

    hipMemsetAsync(d_out, 0, (size_t)out_size * sizeof(float), stream);

    const long WBTOT = (long)NCHT * 8192;                // 966,656 elems
    const size_t need = (size_t)(XPTOT + WBTOT) * 2;     // ~17.7 MB

    if (ws_size >= need) {
        unsigned short* xp = (unsigned short*)d_ws;
        unsigned short* wbb = xp + XPTOT;

        pack_x_kernel<<<7683, 256, 0, stream>>>(x, xp);          // 1,966,848/256 exact
        pack_w_kernel<<<472, 256, 0, stream>>>(W1, W2, W3, wbb); // 120,832/256 exact
        convgemm_kernel<<<256, 512, 0, stream>>>(xp, wbb, b1, b2, b3, out);
    } else {
        dim3 grid(64, 8, 3);
        convmax_fallback<<<grid, 256, 0, stream>>>(x, W1, W2, W3, b1, b2, b3, out);
    }
}

// Round 8
// 86.341 us; speedup vs baseline: 1.5405x; 1.5405x over previous
//
#include <hip/hip_runtime.h>
#include <hip/hip_bf16.h>

#define SEQ 394
#define EMB 300
#define EMBP 312                          // 624B rows: 16B-aligned, bank-balanced stride
#define NROWS (64 * SEQ)                  // 25216
#define XPTOT ((long)NROWS * EMBP)        // 7,867,392 elems
#define NCHT 118                          // chunks of 32: 30 (br0) + 39 (br1) + 49 (br2)
#define CBE0 29                           // last chunk of br0 (odd)
#define CBE1 68                           // last chunk of br1 (even)
#define XELEM 41472                       // 5184 granules; covers 132 rows x 312 + pad

typedef __attribute__((ext_vector_type(8))) short short8;
typedef __attribute__((ext_vector_type(4))) float f32x4;

__device__ __forceinline__ unsigned short f2b(float f) {
    unsigned u = __float_as_uint(f);
    u += 0x7FFFu + ((u >> 16) & 1u);   // RNE to bf16
    return (unsigned short)(u >> 16);
}

__device__ __forceinline__ void gload_lds16(const void* g, void* l) {
    __builtin_amdgcn_global_load_lds(
        (const __attribute__((address_space(1))) void*)g,
        (__attribute__((address_space(3))) void*)l, 16, 0, 0);
}

// ---------------- pack kernels ----------------

// x fp32 [25216][300] -> xp bf16 [25216][312], cols 300..311 zero
__global__ __launch_bounds__(256)
void pack_x_kernel(const float* __restrict__ x, unsigned short* __restrict__ xp)
{
    long q = (long)blockIdx.x * 256 + threadIdx.x;       // quad of 4 elems; 1,966,848 exact
    int row = (int)(q / 78);
    int c4  = ((int)(q - (long)row * 78)) * 4;
    ushort4 u;
    if (c4 < 300) {
        float4 v = *(const float4*)(x + (long)row * 300 + c4);
        u = make_ushort4(f2b(v.x), f2b(v.y), f2b(v.z), f2b(v.w));
    } else {
        u = make_ushort4(0, 0, 0, 0);
    }
    *(ushort4*)(xp + q * 4) = u;
}

// W -> A-fragment-ordered blob: granule G = (c*16 + g)*64 + l holds
// W[f = g*16 + (l&15)][k = kof(c) + (l>>4)*8 + j] over the 312-padded k-axis
// (zero where r>=n or e>=300). One fgroup = 16 filters x 32 k = 1KB contiguous.
__global__ __launch_bounds__(256)
void pack_w_kernel(const float* __restrict__ W1, const float* __restrict__ W2,
                   const float* __restrict__ W3, unsigned short* __restrict__ wb)
{
    int G = blockIdx.x * 256 + threadIdx.x;              // 120,832 total (exact)
    int l  = G & 63;
    int g  = (G >> 6) & 15;
    int c  = G >> 10;
    const float* Wg; int n, cb;
    if (c <= CBE0)      { Wg = W1; n = 3; cb = 0;        }
    else if (c <= CBE1) { Wg = W2; n = 4; cb = CBE0 + 1; }
    else                { Wg = W3; n = 5; cb = CBE1 + 1; }
    const int K = n * 300;
    const int f = g * 16 + (l & 15);
    const int kl = (c - cb) * 32 + (l >> 4) * 8;
    unsigned short v[8];
#pragma unroll
    for (int j = 0; j < 8; ++j) {
        int kk = kl + j;
        int r  = kk / EMBP;
        int e  = kk - r * EMBP;
        v[j] = (r < n && e < 300) ? f2b(Wg[(long)f * K + r * 300 + e]) : (unsigned short)0;
    }
    unsigned short* dst = wb + (long)G * 8;
    *(ushort4*)dst       = make_ushort4(v[0], v[1], v[2], v[3]);
    *(ushort4*)(dst + 4) = make_ushort4(v[4], v[5], v[6], v[7]);
}

// ---------------- main kernel ----------------
// Grid 256 = batch(64) x wtile(4: woff 0/88/176/263, 128 slots; overlaps idempotent
// under max). 1024 thr = 16 waves = 8 fsets(32f) x 2 wsets(64w); 4 waves/SIMD.
// X resident in LDS (sole LDS user, bank-balanced 624B stride). W loaded straight
// into registers from the fragment-ordered blob (compiler-counted vmcnt, depth-2).
// Zero barriers after the X fill.

__global__ __launch_bounds__(1024, 1)
void convgemm_kernel(const unsigned short* __restrict__ xp,
                     const unsigned short* __restrict__ wb,
                     const float* __restrict__ b1, const float* __restrict__ b2,
                     const float* __restrict__ b3,
                     float* __restrict__ out)
{
    __shared__ unsigned short X[XELEM];                  // 82,944 B

    const int tid  = threadIdx.x;
    const int lane = tid & 63;
    const int wid  = tid >> 6;
    const int wfs  = wid >> 1;                           // filter-set 0..7 (32f each)
    const int ws   = wid & 1;                            // window-set 0..1 (64w each)
    const int lr   = lane & 15, lg = lane >> 4;
    const int b    = blockIdx.x >> 2;
    const int ti   = blockIdx.x & 3;
    const int woff = (ti == 0) ? 0 : (ti == 1) ? 88 : (ti == 2) ? 176 : 263;

    // ---- prologue: fill resident X (rows woff..woff+131, clamped at buffer end) ----
    {
        const long xbase = ((long)b * SEQ + woff) * EMBP;    // granule-aligned (312 = 39*8)
        const long slim  = XPTOT - 8;
#pragma unroll
        for (int rd = 0; rd < 6; ++rd) {
            int gbase = rd * 1024 + wid * 64;                // wave-uniform
            if (gbase < 5184) {                              // rd=5: only wid 0
                long se = xbase + (long)(gbase + lane) * 8;
                if (se > slim) se = slim;                    // finite garbage; masked later
                gload_lds16(xp + se, &X[gbase * 8]);
            }
        }
    }
    __syncthreads();

    // ---- W fragment loads: global -> registers, 2 x 1KB coalesced per chunk ----
    const unsigned short* wp0 = wb + ((long)(wfs * 2) * 64 + lane) * 8;
    auto LDW = [&](int c, short8 w[2]) {
        const short8* p = (const short8*)(wp0 + (long)c * 8192);
        w[0] = p[0];                                     // fgroup 2*wfs
        w[1] = p[64];                                    // fgroup 2*wfs+1 (+1KB)
    };

    // ---- bx reads: one base pointer + compile-time offsets ----
    const unsigned short* xr = &X[(ws * 64 + lr) * EMBP + lg * 8];
    auto RDBX = [&](int ko, short8 bx[4]) {
        bx[0] = *(const short8*)(xr + ko);
        bx[1] = *(const short8*)(xr + ko + 16 * EMBP);
        bx[2] = *(const short8*)(xr + ko + 32 * EMBP);
        bx[3] = *(const short8*)(xr + ko + 48 * EMBP);
    };

    f32x4 acc[2][4];
#pragma unroll
    for (int i = 0; i < 2; ++i)
#pragma unroll
        for (int j = 0; j < 4; ++j)
            acc[i][j] = (f32x4)0.0f;

    auto MFMA8 = [&](short8 w[2], short8 bx[4]) {
#pragma unroll
        for (int mi = 0; mi < 2; ++mi)
#pragma unroll
            for (int ni = 0; ni < 4; ++ni)
                acc[mi][ni] = __builtin_amdgcn_mfma_f32_16x16x32_bf16(w[mi], bx[ni], acc[mi][ni], 0, 0, 0);
    };

    auto EPI = [&](int br) {
        const float* bg = (br == 0) ? b1 : (br == 1) ? b2 : b3;
        const int Nw = 391 - br;
        const int ob = b * 768 + br * 256;
#pragma unroll
        for (int mi = 0; mi < 2; ++mi) {
#pragma unroll
            for (int r = 0; r < 4; ++r) {
                const int d = wfs * 32 + mi * 16 + lg * 4 + r;       // C/D row = lg*4+r
                const float bv = bg[d];
                float m = 0.f;
#pragma unroll
                for (int ni = 0; ni < 4; ++ni) {
                    int w = woff + ws * 64 + ni * 16 + lr;           // C/D col = lr
                    float v = fmaxf(acc[mi][ni][r] + bv, 0.f);
                    if (w >= Nw) v = 0.f;
                    m = fmaxf(m, v);
                }
#pragma unroll
                for (int off = 1; off < 16; off <<= 1)
                    m = fmaxf(m, __shfl_xor(m, off));
                if (lr == 0)
                    atomicMax((int*)(out + ob + d), __float_as_int(m));
            }
        }
#pragma unroll
        for (int i = 0; i < 2; ++i)
#pragma unroll
            for (int j = 0; j < 4; ++j)
                acc[i][j] = (f32x4)0.0f;
    };

    auto KOF = [](int t) {
        return (t >= 69) ? (t - 69) * 32 : (t >= 30) ? (t - 30) * 32 : t * 32;
    };

    short8 wA[2], wB[2], bxA[4], bxB[4];
    LDW(0, wA); LDW(1, wB);
    RDBX(0, bxA);

    for (int c = 0; c < NCHT; c += 2) {
        // ---- even body: compute chunk c (wA,bxA); prefetch bx(c+1), W(c+2) ----
        RDBX(KOF(c + 1), bxB);                           // c+1 <= 117 always
        MFMA8(wA, bxA);
        {
            int t = (c + 2 < NCHT) ? c + 2 : NCHT - 1;   // clamp: stable issue count
            LDW(t, wA);
        }
        if (c == CBE1) EPI(1);                           // 68 even

        // ---- odd body: compute chunk c+1 (wB,bxB); prefetch bx(c+2), W(c+3) ----
        {
            int t = (c + 2 < NCHT) ? c + 2 : NCHT - 1;
            RDBX(KOF(t), bxA);
        }
        MFMA8(wB, bxB);
        {
            int t = (c + 3 < NCHT) ? c + 3 : NCHT - 1;
            LDW(t, wB);
        }
        if (c + 1 == CBE0) EPI(0);                       // 29 odd
        if (c + 1 == NCHT - 1) EPI(2);                   // 117 odd
    }
}

// ---------------- fallback (no-workspace path) ----------------

__device__ __forceinline__ void load_chunk(const float* __restrict__ Wg,
                                           const float* __restrict__ xb,
                                           int K, int dbase, int i0, int k0, int tid,
                                           float4 wv[4], float4 xv[4])
{
#pragma unroll
    for (int i = 0; i < 4; ++i) {
        int fi  = tid + (i << 8);
        int row = fi >> 3;
        int c4  = (fi & 7) << 2;
        int col = k0 + c4;
        if (col < K)
            wv[i] = *(const float4*)(Wg + (long)(dbase + row) * K + col);
        else
            wv[i] = make_float4(0.f, 0.f, 0.f, 0.f);
        int off = (i0 + row) * EMB + col;
        int lim = SEQ * EMB - 4;
        if (off > lim) off = lim;
        xv[i] = *(const float4*)(xb + off);
    }
}

__device__ __forceinline__ void write_chunk(unsigned short (*Wb)[40],
                                            unsigned short (*Xb)[40],
                                            int tid, const float4 wv[4], const float4 xv[4])
{
#pragma unroll
    for (int i = 0; i < 4; ++i) {
        int fi  = tid + (i << 8);
        int row = fi >> 3;
        int c4  = (fi & 7) << 2;
        *(ushort4*)&Wb[row][c4] = make_ushort4(f2b(wv[i].x), f2b(wv[i].y), f2b(wv[i].z), f2b(wv[i].w));
        *(ushort4*)&Xb[row][c4] = make_ushort4(f2b(xv[i].x), f2b(xv[i].y), f2b(xv[i].z), f2b(xv[i].w));
    }
}

__global__ __launch_bounds__(256, 2)
void convmax_fallback(const float* __restrict__ x,
                      const float* __restrict__ W1, const float* __restrict__ W2,
                      const float* __restrict__ W3,
                      const float* __restrict__ b1, const float* __restrict__ b2,
                      const float* __restrict__ b3,
                      float* __restrict__ out)
{
    const int br = blockIdx.z;
    const int K  = (br == 0) ? 900 : (br == 1) ? 1200 : 1500;
    const int Nw = SEQ - 3 - br;
    const float* Wg = (br == 0) ? W1 : (br == 1) ? W2 : W3;
    const float* bg = (br == 0) ? b1 : (br == 1) ? b2 : b3;
    const int b  = blockIdx.x;
    const int mt = blockIdx.y >> 2;
    const int nt = blockIdx.y & 3;
    const int dbase = mt * 128;
    const int i0    = nt * 128;
    const float* xb = x + b * (SEQ * EMB);
    const int nch = (K + 31) >> 5;

    __shared__ unsigned short Wl[2][128][40];
    __shared__ unsigned short Xl[2][128][40];

    const int tid  = threadIdx.x;
    const int lane = tid & 63;
    const int wid  = tid >> 6;
    const int wr = wid >> 1, wc = wid & 1;
    const int lr = lane & 15, lg = lane >> 4;

    f32x4 acc[4][4];
#pragma unroll
    for (int i = 0; i < 4; ++i)
#pragma unroll
        for (int j = 0; j < 4; ++j)
            acc[i][j] = (f32x4)0.0f;

    {
        float4 wv[4], xv[4];
        load_chunk(Wg, xb, K, dbase, i0, 0, tid, wv, xv);
        write_chunk(Wl[0], Xl[0], tid, wv, xv);
    }
    __syncthreads();

    for (int c = 0; c < nch; ++c) {
        const int cur = c & 1;
        float4 wv[4], xv[4];
        const bool pf = (c + 1 < nch);
        if (pf) load_chunk(Wg, xb, K, dbase, i0, (c + 1) << 5, tid, wv, xv);

        short8 af[4], bfr[4];
#pragma unroll
        for (int mi = 0; mi < 4; ++mi)
            af[mi] = *(const short8*)&Wl[cur][wr * 64 + mi * 16 + lr][lg * 8];
#pragma unroll
        for (int ni = 0; ni < 4; ++ni)
            bfr[ni] = *(const short8*)&Xl[cur][wc * 64 + ni * 16 + lr][lg * 8];
#pragma unroll
        for (int mi = 0; mi < 4; ++mi)
#pragma unroll
            for (int ni = 0; ni < 4; ++ni)
                acc[mi][ni] = __builtin_amdgcn_mfma_f32_16x16x32_bf16(af[mi], bfr[ni], acc[mi][ni], 0, 0, 0);

        if (pf) write_chunk(Wl[cur ^ 1], Xl[cur ^ 1], tid, wv, xv);
        __syncthreads();
    }

    const int ob = b * 768 + br * 256;
#pragma unroll
    for (int mi = 0; mi < 4; ++mi) {
#pragma unroll
        for (int rI = 0; rI < 4; ++rI) {
            const int d = dbase + wr * 64 + mi * 16 + lg * 4 + rI;
            const float bv = bg[d];
            float m = 0.f;
#pragma unroll
            for (int ni = 0; ni < 4; ++ni) {
                int win = i0 + wc * 64 + ni * 16 + lr;
                float v = acc[mi][ni][rI] + bv;
                v = fmaxf(v, 0.f);
                if (win >= Nw) v = 0.f;
                m = fmaxf(m, v);
            }
#pragma unroll
            for (int off = 1; off < 16; off <<= 1)
                m = fmaxf(m, __shfl_xor(m, off));
            if (lr == 0)
                atomicMax((int*)(out + ob + d), __float_as_int(m));
        }
    }
}

// ---------------- launch ----------------

extern "C" void kernel_launch(void* const* d_in, const int* in_sizes, int n_in,
                              void* d_out, int out_size, void* d_ws, size_t ws_size,
                              hipStream_t stream) {
    const float* x  = (const float*)d_in[0];
    const float* W1 = (const float*)d_in[1];
    const float* W2 = (const float*)d_in[2];
    const float* W3 = (const float*)d_in[3];
    const float* b1 = (const float*)d_in[4];
    const float* b2 = (const float*)d_in[5];
    const float* b3 = (const float*)d_in[6];
    float* out = (float*)d_out;

    hipMemsetAsync(d_out, 0, (size_t)out_size * sizeof(float), stream);

    const long WBTOT = (long)NCHT * 8192;                // 966,656 elems
    const size_t need = (size_t)(XPTOT + WBTOT) * 2;     // ~17.7 MB

    if (ws_size >= need) {
        unsigned short* xp = (unsigned short*)d_ws;
        unsigned short* wbb = xp + XPTOT;

        pack_x_kernel<<<7683, 256, 0, stream>>>(x, xp);          // 1,966,848/256 exact
        pack_w_kernel<<<472, 256, 0, stream>>>(W1, W2, W3, wbb); // 120,832/256 exact
        convgemm_kernel<<<256, 1024, 0, stream>>>(xp, wbb, b1, b2, b3, out);
    } else {
        dim3 grid(64, 8, 3);
        convmax_fallback<<<grid, 256, 0, stream>>>(x, W1, W2, W3, b1, b2, b3, out);
    }
}

// Round 9
// 84.998 us; speedup vs baseline: 1.5649x; 1.0158x over previous
//
#include <hip/hip_runtime.h>
#include <hip/hip_bf16.h>

#define SEQ 394
#define EMB 300
#define EMBP 312                          // 624B rows: 16B-aligned, bank-balanced stride
#define NROWS (64 * SEQ)                  // 25216
#define XPTOT ((long)NROWS * EMBP)        // 7,867,392 elems
#define NCHT 118                          // blob chunks: br0 0..29, br1 30..68, br2 69..117
#define CBE0 29
#define CBE1 68
#define XELEM 41472                       // 5184 granules; max used elem 41192

typedef __attribute__((ext_vector_type(8))) short short8;
typedef __attribute__((ext_vector_type(4))) float f32x4;

__device__ __forceinline__ unsigned short f2b(float f) {
    unsigned u = __float_as_uint(f);
    u += 0x7FFFu + ((u >> 16) & 1u);   // RNE to bf16
    return (unsigned short)(u >> 16);
}

__device__ __forceinline__ void gload_lds16(const void* g, void* l) {
    __builtin_amdgcn_global_load_lds(
        (const __attribute__((address_space(1))) void*)g,
        (__attribute__((address_space(3))) void*)l, 16, 0, 0);
}

// ---------------- pack kernels ----------------

// x fp32 [25216][300] -> xp bf16 [25216][312], cols 300..311 zero
__global__ __launch_bounds__(256)
void pack_x_kernel(const float* __restrict__ x, unsigned short* __restrict__ xp)
{
    long q = (long)blockIdx.x * 256 + threadIdx.x;       // quad of 4 elems; 1,966,848 exact
    int row = (int)(q / 78);
    int c4  = ((int)(q - (long)row * 78)) * 4;
    ushort4 u;
    if (c4 < 300) {
        float4 v = *(const float4*)(x + (long)row * 300 + c4);
        u = make_ushort4(f2b(v.x), f2b(v.y), f2b(v.z), f2b(v.w));
    } else {
        u = make_ushort4(0, 0, 0, 0);
    }
    *(ushort4*)(xp + q * 4) = u;
}

// W -> A-fragment-ordered blob: granule G = (c*16 + g)*64 + l holds
// W[f = g*16 + (l&15)][k = kof(c) + (l>>4)*8 + j] over the 312-padded k-axis
// (zero where r>=n or e>=300). One fgroup = 16 filters x 32 k = 1KB contiguous.
__global__ __launch_bounds__(256)
void pack_w_kernel(const float* __restrict__ W1, const float* __restrict__ W2,
                   const float* __restrict__ W3, unsigned short* __restrict__ wb)
{
    int G = blockIdx.x * 256 + threadIdx.x;              // 120,832 total (exact)
    int l  = G & 63;
    int g  = (G >> 6) & 15;
    int c  = G >> 10;
    const float* Wg; int n, cb;
    if (c <= CBE0)      { Wg = W1; n = 3; cb = 0;        }
    else if (c <= CBE1) { Wg = W2; n = 4; cb = CBE0 + 1; }
    else                { Wg = W3; n = 5; cb = CBE1 + 1; }
    const int K = n * 300;
    const int f = g * 16 + (l & 15);
    const int kl = (c - cb) * 32 + (l >> 4) * 8;
    unsigned short v[8];
#pragma unroll
    for (int j = 0; j < 8; ++j) {
        int kk = kl + j;
        int r  = kk / EMBP;
        int e  = kk - r * EMBP;
        v[j] = (r < n && e < 300) ? f2b(Wg[(long)f * K + r * 300 + e]) : (unsigned short)0;
    }
    unsigned short* dst = wb + (long)G * 8;
    *(ushort4*)dst       = make_ushort4(v[0], v[1], v[2], v[3]);
    *(ushort4*)(dst + 4) = make_ushort4(v[4], v[5], v[6], v[7]);
}

// ---------------- main kernel ----------------
// Grid 256 = batch(64) x wtile(4: woff 0/88/176/263; overlaps idempotent under max).
// 1024 thr = 16 waves = 8 fsets(32f) x 2 wsets(64w); 4 waves/SIMD, 1 block/CU.
// X resident in LDS. W global->registers (fragment-ordered blob, depth-2).
// KEY: branches share bx — br1+br2 run CONCURRENTLY on one bx read (chunks 0..38),
// then br2 tail solo (10), then br0 solo (30): 79 bx chunk-reads instead of 118.

__global__ __launch_bounds__(1024, 1)
void convgemm_kernel(const unsigned short* __restrict__ xp,
                     const unsigned short* __restrict__ wb,
                     const float* __restrict__ b1, const float* __restrict__ b2,
                     const float* __restrict__ b3,
                     float* __restrict__ out)
{
    __shared__ unsigned short X[XELEM];                  // 82,944 B

    const int tid  = threadIdx.x;
    const int lane = tid & 63;
    const int wid  = tid >> 6;
    const int wfs  = wid >> 1;                           // filter-set 0..7 (32f each)
    const int ws   = wid & 1;                            // window-set 0..1 (64w each)
    const int lr   = lane & 15, lg = lane >> 4;
    const int b    = blockIdx.x >> 2;
    const int ti   = blockIdx.x & 3;
    const int woff = (ti == 0) ? 0 : (ti == 1) ? 88 : (ti == 2) ? 176 : 263;

    // ---- prologue: fill resident X ----
    {
        const long xbase = ((long)b * SEQ + woff) * EMBP;    // granule-aligned (312 = 39*8)
        const long slim  = XPTOT - 8;
#pragma unroll
        for (int rd = 0; rd < 6; ++rd) {
            int gbase = rd * 1024 + wid * 64;                // wave-uniform
            if (gbase < 5184) {
                long se = xbase + (long)(gbase + lane) * 8;
                if (se > slim) se = slim;                    // finite garbage; masked later
                gload_lds16(xp + se, &X[gbase * 8]);
            }
        }
    }
    __syncthreads();

    // ---- W fragment loads: global -> registers, 2 x 1KB coalesced per chunk ----
    const unsigned short* wp0 = wb + ((long)(wfs * 2) * 64 + lane) * 8;
    auto LDW = [&](int c, short8 (&w)[2]) {
        const short8* p = (const short8*)(wp0 + (long)c * 8192);
        w[0] = p[0];                                     // fgroup 2*wfs
        w[1] = p[64];                                    // fgroup 2*wfs+1 (+1KB)
    };

    // ---- bx reads: one base pointer + compile-time offsets ----
    const unsigned short* xr = &X[(ws * 64 + lr) * EMBP + lg * 8];
    auto RDBX = [&](int ko, short8 (&bx)[4]) {
        bx[0] = *(const short8*)(xr + ko);
        bx[1] = *(const short8*)(xr + ko + 16 * EMBP);
        bx[2] = *(const short8*)(xr + ko + 32 * EMBP);
        bx[3] = *(const short8*)(xr + ko + 48 * EMBP);
    };

    auto MFMA8 = [&](const short8 (&w)[2], const short8 (&bx)[4], f32x4 (&acc)[2][4]) {
#pragma unroll
        for (int mi = 0; mi < 2; ++mi)
#pragma unroll
            for (int ni = 0; ni < 4; ++ni)
                acc[mi][ni] = __builtin_amdgcn_mfma_f32_16x16x32_bf16(w[mi], bx[ni], acc[mi][ni], 0, 0, 0);
    };

    auto EPI = [&](int br, f32x4 (&acc)[2][4]) {
        const float* bg = (br == 0) ? b1 : (br == 1) ? b2 : b3;
        const int Nw = 391 - br;
        const int ob = b * 768 + br * 256;
#pragma unroll
        for (int mi = 0; mi < 2; ++mi) {
#pragma unroll
            for (int r = 0; r < 4; ++r) {
                const int d = wfs * 32 + mi * 16 + lg * 4 + r;       // C/D row = lg*4+r
                const float bv = bg[d];
                float m = 0.f;
#pragma unroll
                for (int ni = 0; ni < 4; ++ni) {
                    int w = woff + ws * 64 + ni * 16 + lr;           // C/D col = lr
                    float v = fmaxf(acc[mi][ni][r] + bv, 0.f);
                    if (w >= Nw) v = 0.f;
                    m = fmaxf(m, v);
                }
#pragma unroll
                for (int off = 1; off < 16; off <<= 1)
                    m = fmaxf(m, __shfl_xor(m, off));
                if (lr == 0)
                    atomicMax((int*)(out + ob + d), __float_as_int(m));
            }
        }
#pragma unroll
        for (int i = 0; i < 2; ++i)
#pragma unroll
            for (int j = 0; j < 4; ++j)
                acc[i][j] = (f32x4)0.0f;
    };

    f32x4 accA[2][4], accB[2][4];
#pragma unroll
    for (int i = 0; i < 2; ++i)
#pragma unroll
        for (int j = 0; j < 4; ++j) {
            accA[i][j] = (f32x4)0.0f;
            accB[i][j] = (f32x4)0.0f;
        }

    short8 w1A[2], w1B[2], w2A[2], w2B[2], bx[4];

    // ======== P1: br1 + br2 paired on shared bx, chunks j = 0..38 ========
    LDW(30, w1A); LDW(69, w2A);
    LDW(31, w1B); LDW(70, w2B);
    for (int j = 0; j < 38; j += 2) {
        RDBX(j * 32, bx);
        MFMA8(w1A, bx, accA);
        MFMA8(w2A, bx, accB);
        { int t = (j + 2 < 39) ? j + 2 : 38; LDW(30 + t, w1A); LDW(69 + t, w2A); }

        RDBX((j + 1) * 32, bx);
        MFMA8(w1B, bx, accA);
        MFMA8(w2B, bx, accB);
        { int t = (j + 3 < 39) ? j + 3 : 38; LDW(30 + t, w1B); LDW(69 + t, w2B); }
    }
    // tail chunk 38 (in A)
    RDBX(38 * 32, bx);
    MFMA8(w1A, bx, accA);
    MFMA8(w2A, bx, accB);

    // prime P2's W pipeline before br1 epilogue (hide L2 latency under EPI)
    LDW(69 + 39, w2A); LDW(69 + 40, w2B);
    EPI(1, accA);

    // ======== P2: br2 tail solo, chunks 39..48 ========
    for (int t = 0; t < 10; t += 2) {
        RDBX((39 + t) * 32, bx);
        MFMA8(w2A, bx, accB);
        { int u = (41 + t < 49) ? 41 + t : 48; LDW(69 + u, w2A); }

        RDBX((40 + t) * 32, bx);
        MFMA8(w2B, bx, accB);
        { int u = (42 + t < 49) ? 42 + t : 48; LDW(69 + u, w2B); }
    }

    // prime P0's W pipeline before br2 epilogue
    LDW(0, w1A); LDW(1, w1B);
    EPI(2, accB);

    // ======== P0: br0 solo, chunks 0..29 (accA reused, cleared by EPI) ========
    for (int j = 0; j < 30; j += 2) {
        RDBX(j * 32, bx);
        MFMA8(w1A, bx, accA);
        { int t = (j + 2 < 30) ? j + 2 : 29; LDW(t, w1A); }

        RDBX((j + 1) * 32, bx);
        MFMA8(w1B, bx, accA);
        { int t = (j + 3 < 30) ? j + 3 : 29; LDW(t, w1B); }
    }
    EPI(0, accA);
}

// ---------------- fallback (no-workspace path) ----------------

__device__ __forceinline__ void load_chunk(const float* __restrict__ Wg,
                                           const float* __restrict__ xb,
                                           int K, int dbase, int i0, int k0, int tid,
                                           float4 wv[4], float4 xv[4])
{
#pragma unroll
    for (int i = 0; i < 4; ++i) {
        int fi  = tid + (i << 8);
        int row = fi >> 3;
        int c4  = (fi & 7) << 2;
        int col = k0 + c4;
        if (col < K)
            wv[i] = *(const float4*)(Wg + (long)(dbase + row) * K + col);
        else
            wv[i] = make_float4(0.f, 0.f, 0.f, 0.f);
        int off = (i0 + row) * EMB + col;
        int lim = SEQ * EMB - 4;
        if (off > lim) off = lim;
        xv[i] = *(const float4*)(xb + off);
    }
}

__device__ __forceinline__ void write_chunk(unsigned short (*Wb)[40],
                                            unsigned short (*Xb)[40],
                                            int tid, const float4 wv[4], const float4 xv[4])
{
#pragma unroll
    for (int i = 0; i < 4; ++i) {
        int fi  = tid + (i << 8);
        int row = fi >> 3;
        int c4  = (fi & 7) << 2;
        *(ushort4*)&Wb[row][c4] = make_ushort4(f2b(wv[i].x), f2b(wv[i].y), f2b(wv[i].z), f2b(wv[i].w));
        *(ushort4*)&Xb[row][c4] = make_ushort4(f2b(xv[i].x), f2b(xv[i].y), f2b(xv[i].z), f2b(xv[i].w));
    }
}

__global__ __launch_bounds__(256, 2)
void convmax_fallback(const float* __restrict__ x,
                      const float* __restrict__ W1, const float* __restrict__ W2,
                      const float* __restrict__ W3,
                      const float* __restrict__ b1, const float* __restrict__ b2,
                      const float* __restrict__ b3,
                      float* __restrict__ out)
{
    const int br = blockIdx.z;
    const int K  = (br == 0) ? 900 : (br == 1) ? 1200 : 1500;
    const int Nw = SEQ - 3 - br;
    const float* Wg = (br == 0) ? W1 : (br == 1) ? W2 : W3;
    const float* bg = (br == 0) ? b1 : (br == 1) ? b2 : b3;
    const int b  = blockIdx.x;
    const int mt = blockIdx.y >> 2;
    const int nt = blockIdx.y & 3;
    const int dbase = mt * 128;
    const int i0    = nt * 128;
    const float* xb = x + b * (SEQ * EMB);
    const int nch = (K + 31) >> 5;

    __shared__ unsigned short Wl[2][128][40];
    __shared__ unsigned short Xl[2][128][40];

    const int tid  = threadIdx.x;
    const int lane = tid & 63;
    const int wid  = tid >> 6;
    const int wr = wid >> 1, wc = wid & 1;
    const int lr = lane & 15, lg = lane >> 4;

    f32x4 acc[4][4];
#pragma unroll
    for (int i = 0; i < 4; ++i)
#pragma unroll
        for (int j = 0; j < 4; ++j)
            acc[i][j] = (f32x4)0.0f;

    {
        float4 wv[4], xv[4];
        load_chunk(Wg, xb, K, dbase, i0, 0, tid, wv, xv);
        write_chunk(Wl[0], Xl[0], tid, wv, xv);
    }
    __syncthreads();

    for (int c = 0; c < nch; ++c) {
        const int cur = c & 1;
        float4 wv[4], xv[4];
        const bool pf = (c + 1 < nch);
        if (pf) load_chunk(Wg, xb, K, dbase, i0, (c + 1) << 5, tid, wv, xv);

        short8 af[4], bfr[4];
#pragma unroll
        for (int mi = 0; mi < 4; ++mi)
            af[mi] = *(const short8*)&Wl[cur][wr * 64 + mi * 16 + lr][lg * 8];
#pragma unroll
        for (int ni = 0; ni < 4; ++ni)
            bfr[ni] = *(const short8*)&Xl[cur][wc * 64 + ni * 16 + lr][lg * 8];
#pragma unroll
        for (int mi = 0; mi < 4; ++mi)
#pragma unroll
            for (int ni = 0; ni < 4; ++ni)
                acc[mi][ni] = __builtin_amdgcn_mfma_f32_16x16x32_bf16(af[mi], bfr[ni], acc[mi][ni], 0, 0, 0);

        if (pf) write_chunk(Wl[cur ^ 1], Xl[cur ^ 1], tid, wv, xv);
        __syncthreads();
    }

    const int ob = b * 768 + br * 256;
#pragma unroll
    for (int mi = 0; mi < 4; ++mi) {
#pragma unroll
        for (int rI = 0; rI < 4; ++rI) {
            const int d = dbase + wr * 64 + mi * 16 + lg * 4 + rI;
            const float bv = bg[d];
            float m = 0.f;
#pragma unroll
            for (int ni = 0; ni < 4; ++ni) {
                int win = i0 + wc * 64 + ni * 16 + lr;
                float v = acc[mi][ni][rI] + bv;
                v = fmaxf(v, 0.f);
                if (win >= Nw) v = 0.f;
                m = fmaxf(m, v);
            }
#pragma unroll
            for (int off = 1; off < 16; off <<= 1)
                m = fmaxf(m, __shfl_xor(m, off));
            if (lr == 0)
                atomicMax((int*)(out + ob + d), __float_as_int(m));
        }
    }
}

// ---------------- launch ----------------

extern "C" void kernel_launch(void* const* d_in, const int* in_sizes, int n_in,
                              void* d_out, int out_size, void* d_ws, size_t ws_size,
                              hipStream_t stream) {
    const float* x  = (const float*)d_in[0];
    const float* W1 = (const float*)d_in[1];
    const float* W2 = (const float*)d_in[2];
    const float* W3 = (const float*)d_in[3];
    const float* b1 = (const float*)d_in[4];
    const float* b2 = (const float*)d_in[5];
    const float* b3 = (const float*)d_in[6];
    float* out = (float*)d_out;

    hipMemsetAsync(d_out, 0, (size_t)out_size * sizeof(float), stream);

    const long WBTOT = (long)NCHT * 8192;                // 966,656 elems
    const size_t need = (size_t)(XPTOT + WBTOT) * 2;     // ~17.7 MB

    if (ws_size >= need) {
        unsigned short* xp = (unsigned short*)d_ws;
        unsigned short* wbb = xp + XPTOT;

        pack_x_kernel<<<7683, 256, 0, stream>>>(x, xp);          // 1,966,848/256 exact
        pack_w_kernel<<<472, 256, 0, stream>>>(W1, W2, W3, wbb); // 120,832/256 exact
        convgemm_kernel<<<256, 1024, 0, stream>>>(xp, wbb, b1, b2, b3, out);
    } else {
        dim3 grid(64, 8, 3);
        convmax_fallback<<<grid, 256, 0, stream>>>(x, W1, W2, W3, b1, b2, b3, out);
    }
}

// Round 11
// 80.615 us; speedup vs baseline: 1.6499x; 1.0544x over previous
//
#include <hip/hip_runtime.h>
#include <hip/hip_bf16.h>

#define SEQ 394
#define EMB 300
#define EMBP 312                          // 624B rows: 16B-aligned
#define NROWS (64 * SEQ)                  // 25216
#define NCHT 118                          // blob chunks: br0 0..29, br1 30..68, br2 69..117
#define CBE0 29
#define CBE1 68
#define XELEM 41472                       // LDS elems; max read elem 41191
#define XGR 5148                          // 132 rows x 39 granules (8 elems each)

typedef __attribute__((ext_vector_type(8))) short short8;
typedef __attribute__((ext_vector_type(4))) float f32x4;

__device__ __forceinline__ unsigned short f2b(float f) {
    unsigned u = __float_as_uint(f);
    u += 0x7FFFu + ((u >> 16) & 1u);   // RNE to bf16
    return (unsigned short)(u >> 16);
}

// ---------------- pack kernel (W only; X conversion fused into GEMM) ----------------

// W -> A-fragment-ordered blob: granule G = (c*16 + g)*64 + l holds
// W[f = g*16 + (l&15)][k = kof(c) + (l>>4)*8 + j] over the 312-padded k-axis
// (zero where r>=n or e>=300). One fgroup = 16 filters x 32 k = 1KB contiguous.
__global__ __launch_bounds__(256)
void pack_w_kernel(const float* __restrict__ W1, const float* __restrict__ W2,
                   const float* __restrict__ W3, unsigned short* __restrict__ wb)
{
    int G = blockIdx.x * 256 + threadIdx.x;              // 120,832 total (exact)
    int l  = G & 63;
    int g  = (G >> 6) & 15;
    int c  = G >> 10;
    const float* Wg; int n, cb;
    if (c <= CBE0)      { Wg = W1; n = 3; cb = 0;        }
    else if (c <= CBE1) { Wg = W2; n = 4; cb = CBE0 + 1; }
    else                { Wg = W3; n = 5; cb = CBE1 + 1; }
    const int K = n * 300;
    const int f = g * 16 + (l & 15);
    const int kl = (c - cb) * 32 + (l >> 4) * 8;
    unsigned short v[8];
#pragma unroll
    for (int j = 0; j < 8; ++j) {
        int kk = kl + j;
        int r  = kk / EMBP;
        int e  = kk - r * EMBP;
        v[j] = (r < n && e < 300) ? f2b(Wg[(long)f * K + r * 300 + e]) : (unsigned short)0;
    }
    unsigned short* dst = wb + (long)G * 8;
    *(ushort4*)dst       = make_ushort4(v[0], v[1], v[2], v[3]);
    *(ushort4*)(dst + 4) = make_ushort4(v[4], v[5], v[6], v[7]);
}

// ---------------- main kernel ----------------
// Grid 256 = batch(64) x wtile(4: woff 0/88/176/263; overlaps idempotent under max).
// 1024 thr = 16 waves = 8 fsets(32f) x 2 wsets(64w); 4 waves/SIMD, 1 block/CU.
// X converted fp32->bf16 into LDS in the prologue (132 rows). W global->registers.
// Cascade (R9-proven): P1 br1+br2 share bx ko 0..38; P2 br2 solo 39..48; P0 br0 0..29.
// Pipeline: bx double-buffered; RDBX(next) -> sched_barrier(0) -> MFMA(cur) pins
// the ds_reads BEFORE the MFMA cluster so lgkm latency hides under MFMAs.

__global__ __launch_bounds__(1024, 1)
void convgemm_kernel(const float* __restrict__ x,
                     const unsigned short* __restrict__ wb,
                     const float* __restrict__ b1, const float* __restrict__ b2,
                     const float* __restrict__ b3,
                     float* __restrict__ out)
{
    __shared__ unsigned short X[XELEM];                  // 82,944 B

    const int tid  = threadIdx.x;
    const int lane = tid & 63;
    const int wid  = tid >> 6;
    const int wfs  = wid >> 1;                           // filter-set 0..7 (32f each)
    const int ws   = wid & 1;                            // window-set 0..1 (64w each)
    const int lr   = lane & 15, lg = lane >> 4;
    const int b    = blockIdx.x >> 2;
    const int ti   = blockIdx.x & 3;
    const int woff = (ti == 0) ? 0 : (ti == 1) ? 88 : (ti == 2) ? 176 : 263;

    // ---- W fragment loads: global -> registers, 2 x 16B per wave per chunk ----
    const unsigned short* wp0 = wb + ((long)(wfs * 2) * 64 + lane) * 8;
    auto LDW = [&](int c, short8 (&w)[2]) {
        const short8* p = (const short8*)(wp0 + (long)c * 8192);
        w[0] = p[0];
        w[1] = p[64];
    };

    short8 w1[2], w2[2];
    LDW(30, w1); LDW(69, w2);                            // P1 primes; hide under X conv

    // ---- fused X conversion: fp32 [132 rows x 300] -> bf16 LDS [132 x 312] ----
    {
        const float* xs = x + ((long)b * SEQ + woff) * 300;
        const long growbase = (long)b * SEQ + woff;
#pragma unroll
        for (int rd = 0; rd < 6; ++rd) {
            int gi = rd * 1024 + tid;                    // granule 0..5147
            if (gi < XGR) {
                int row = gi / 39;
                int g   = gi - row * 39;
                const float* src = xs + (long)gi * 8 - 12 * row;   // = row*300 + g*8
                float4 v0 = make_float4(0.f, 0.f, 0.f, 0.f);
                float4 v1 = make_float4(0.f, 0.f, 0.f, 0.f);
                if (growbase + row < NROWS) {            // last tile of last batch: zero row 131
                    if (g < 37) {                        // elems g*8..g*8+7 all < 300
                        v0 = *(const float4*)src;
                        v1 = *(const float4*)(src + 4);
                    } else if (g == 37) {                // 296..299 real, 300..303 pad
                        v0 = *(const float4*)src;
                    }                                    // g==38: all pad
                }
                *(ushort4*)&X[gi * 8]     = make_ushort4(f2b(v0.x), f2b(v0.y), f2b(v0.z), f2b(v0.w));
                *(ushort4*)&X[gi * 8 + 4] = make_ushort4(f2b(v1.x), f2b(v1.y), f2b(v1.z), f2b(v1.w));
            }
        }
    }
    __syncthreads();

    // ---- bx reads: one base pointer + compile-time offsets ----
    const unsigned short* xr = &X[(ws * 64 + lr) * EMBP + lg * 8];
    auto RDBX = [&](int ko, short8 (&bx)[4]) {
        bx[0] = *(const short8*)(xr + ko);
        bx[1] = *(const short8*)(xr + ko + 16 * EMBP);
        bx[2] = *(const short8*)(xr + ko + 32 * EMBP);
        bx[3] = *(const short8*)(xr + ko + 48 * EMBP);
    };

    auto MFMA8 = [&](const short8 (&w)[2], const short8 (&bx)[4], f32x4 (&acc)[2][4]) {
#pragma unroll
        for (int mi = 0; mi < 2; ++mi)
#pragma unroll
            for (int ni = 0; ni < 4; ++ni)
                acc[mi][ni] = __builtin_amdgcn_mfma_f32_16x16x32_bf16(w[mi], bx[ni], acc[mi][ni], 0, 0, 0);
    };

    auto EPI = [&](int br, f32x4 (&acc)[2][4]) {
        const float* bg = (br == 0) ? b1 : (br == 1) ? b2 : b3;
        const int Nw = 391 - br;
        const int ob = b * 768 + br * 256;
#pragma unroll
        for (int mi = 0; mi < 2; ++mi) {
#pragma unroll
            for (int r = 0; r < 4; ++r) {
                const int d = wfs * 32 + mi * 16 + lg * 4 + r;       // C/D row = lg*4+r
                const float bv = bg[d];
                float m = 0.f;
#pragma unroll
                for (int ni = 0; ni < 4; ++ni) {
                    int w = woff + ws * 64 + ni * 16 + lr;           // C/D col = lr
                    float v = fmaxf(acc[mi][ni][r] + bv, 0.f);
                    if (w >= Nw) v = 0.f;
                    m = fmaxf(m, v);
                }
#pragma unroll
                for (int off = 1; off < 16; off <<= 1)
                    m = fmaxf(m, __shfl_xor(m, off));
                if (lr == 0)
                    atomicMax((int*)(out + ob + d), __float_as_int(m));
            }
        }
#pragma unroll
        for (int i = 0; i < 2; ++i)
#pragma unroll
            for (int j = 0; j < 4; ++j)
                acc[i][j] = (f32x4)0.0f;
    };

    f32x4 accA[2][4], accB[2][4];
#pragma unroll
    for (int i = 0; i < 2; ++i)
#pragma unroll
        for (int j = 0; j < 4; ++j) {
            accA[i][j] = (f32x4)0.0f;
            accB[i][j] = (f32x4)0.0f;
        }

    short8 bxA[4], bxB[4];
    RDBX(0, bxA);

    // ======== P1: ko 0..38, br1 (accA) + br2 (accB) share bx ========
    for (int j = 0; j < 38; j += 2) {
        RDBX((j + 1) * 32, bxB);                         // next chunk's bx in flight
        __builtin_amdgcn_sched_barrier(0);
        __builtin_amdgcn_s_setprio(1);
        MFMA8(w1, bxA, accA);
        MFMA8(w2, bxA, accB);
        __builtin_amdgcn_s_setprio(0);
        LDW(30 + j + 1, w1); LDW(69 + j + 1, w2);        // W for ko j+1

        RDBX((j + 2) * 32, bxA);                         // j+2 <= 38
        __builtin_amdgcn_sched_barrier(0);
        __builtin_amdgcn_s_setprio(1);
        MFMA8(w1, bxB, accA);
        MFMA8(w2, bxB, accB);
        __builtin_amdgcn_s_setprio(0);
        LDW(30 + j + 2, w1); LDW(69 + j + 2, w2);        // W for ko j+2
    }
    // tail ko 38 (bxA, w1=blob68, w2=blob107)
    __builtin_amdgcn_s_setprio(1);
    MFMA8(w1, bxA, accA);
    MFMA8(w2, bxA, accB);
    __builtin_amdgcn_s_setprio(0);

    // prime P2 (w2 <- blob108 = ko39; bxB <- ko39) before br1 epilogue
    LDW(108, w2);
    RDBX(39 * 32, bxB);
    EPI(1, accA);                                        // accA freed for br0

    // ======== P2: ko 39..48, br2 solo (accB) ========
    for (int u = 0; u < 10; u += 2) {
        RDBX((40 + u) * 32, bxA);                        // <= 48
        __builtin_amdgcn_sched_barrier(0);
        __builtin_amdgcn_s_setprio(1);
        MFMA8(w2, bxB, accB);                            // ko 39+u
        __builtin_amdgcn_s_setprio(0);
        LDW(109 + u, w2);                                // ko 40+u

        { int t = (41 + u <= 48) ? 41 + u : 48; RDBX(t * 32, bxB); }
        __builtin_amdgcn_sched_barrier(0);
        __builtin_amdgcn_s_setprio(1);
        MFMA8(w2, bxA, accB);                            // ko 40+u
        __builtin_amdgcn_s_setprio(0);
        { int t = (110 + u <= 117) ? 110 + u : 117; LDW(t, w2); }
    }

    // prime P0 (w1 <- blob0; bxA <- ko0) before br2 epilogue
    LDW(0, w1);
    RDBX(0, bxA);
    EPI(2, accB);

    // ======== P0: ko 0..29, br0 solo (accA) ========
    for (int j = 0; j < 30; j += 2) {
        RDBX((j + 1) * 32, bxB);
        __builtin_amdgcn_sched_barrier(0);
        __builtin_amdgcn_s_setprio(1);
        MFMA8(w1, bxA, accA);                            // ko j
        __builtin_amdgcn_s_setprio(0);
        LDW(j + 1, w1);

        { int t = (j + 2 <= 29) ? j + 2 : 29; RDBX(t * 32, bxA); }
        __builtin_amdgcn_sched_barrier(0);
        __builtin_amdgcn_s_setprio(1);
        MFMA8(w1, bxB, accA);                            // ko j+1
        __builtin_amdgcn_s_setprio(0);
        { int t = (j + 2 <= 29) ? j + 2 : 29; LDW(t, w1); }
    }
    EPI(0, accA);
}

// ---------------- fallback (no-workspace path) ----------------

__device__ __forceinline__ void load_chunk(const float* __restrict__ Wg,
                                           const float* __restrict__ xb,
                                           int K, int dbase, int i0, int k0, int tid,
                                           float4 wv[4], float4 xv[4])
{
#pragma unroll
    for (int i = 0; i < 4; ++i) {
        int fi  = tid + (i << 8);
        int row = fi >> 3;
        int c4  = (fi & 7) << 2;
        int col = k0 + c4;
        if (col < K)
            wv[i] = *(const float4*)(Wg + (long)(dbase + row) * K + col);
        else
            wv[i] = make_float4(0.f, 0.f, 0.f, 0.f);
        int off = (i0 + row) * EMB + col;
        int lim = SEQ * EMB - 4;
        if (off > lim) off = lim;
        xv[i] = *(const float4*)(xb + off);
    }
}

__device__ __forceinline__ void write_chunk(unsigned short (*Wb)[40],
                                            unsigned short (*Xb)[40],
                                            int tid, const float4 wv[4], const float4 xv[4])
{
#pragma unroll
    for (int i = 0; i < 4; ++i) {
        int fi  = tid + (i << 8);
        int row = fi >> 3;
        int c4  = (fi & 7) << 2;
        *(ushort4*)&Wb[row][c4] = make_ushort4(f2b(wv[i].x), f2b(wv[i].y), f2b(wv[i].z), f2b(wv[i].w));
        *(ushort4*)&Xb[row][c4] = make_ushort4(f2b(xv[i].x), f2b(xv[i].y), f2b(xv[i].z), f2b(xv[i].w));
    }
}

__global__ __launch_bounds__(256, 2)
void convmax_fallback(const float* __restrict__ x,
                      const float* __restrict__ W1, const float* __restrict__ W2,
                      const float* __restrict__ W3,
                      const float* __restrict__ b1, const float* __restrict__ b2,
                      const float* __restrict__ b3,
                      float* __restrict__ out)
{
    const int br = blockIdx.z;
    const int K  = (br == 0) ? 900 : (br == 1) ? 1200 : 1500;
    const int Nw = SEQ - 3 - br;
    const float* Wg = (br == 0) ? W1 : (br == 1) ? W2 : W3;
    const float* bg = (br == 0) ? b1 : (br == 1) ? b2 : b3;
    const int b  = blockIdx.x;
    const int mt = blockIdx.y >> 2;
    const int nt = blockIdx.y & 3;
    const int dbase = mt * 128;
    const int i0    = nt * 128;
    const float* xb = x + b * (SEQ * EMB);
    const int nch = (K + 31) >> 5;

    __shared__ unsigned short Wl[2][128][40];
    __shared__ unsigned short Xl[2][128][40];

    const int tid  = threadIdx.x;
    const int lane = tid & 63;
    const int wid  = tid >> 6;
    const int wr = wid >> 1, wc = wid & 1;
    const int lr = lane & 15, lg = lane >> 4;

    f32x4 acc[4][4];
#pragma unroll
    for (int i = 0; i < 4; ++i)
#pragma unroll
        for (int j = 0; j < 4; ++j)
            acc[i][j] = (f32x4)0.0f;

    {
        float4 wv[4], xv[4];
        load_chunk(Wg, xb, K, dbase, i0, 0, tid, wv, xv);
        write_chunk(Wl[0], Xl[0], tid, wv, xv);
    }
    __syncthreads();

    for (int c = 0; c < nch; ++c) {
        const int cur = c & 1;
        float4 wv[4], xv[4];
        const bool pf = (c + 1 < nch);
        if (pf) load_chunk(Wg, xb, K, dbase, i0, (c + 1) << 5, tid, wv, xv);

        short8 af[4], bfr[4];
#pragma unroll
        for (int mi = 0; mi < 4; ++mi)
            af[mi] = *(const short8*)&Wl[cur][wr * 64 + mi * 16 + lr][lg * 8];
#pragma unroll
        for (int ni = 0; ni < 4; ++ni)
            bfr[ni] = *(const short8*)&Xl[cur][wc * 64 + ni * 16 + lr][lg * 8];
#pragma unroll
        for (int mi = 0; mi < 4; ++mi)
#pragma unroll
            for (int ni = 0; ni < 4; ++ni)
                acc[mi][ni] = __builtin_amdgcn_mfma_f32_16x16x32_bf16(af[mi], bfr[ni], acc[mi][ni], 0, 0, 0);

        if (pf) write_chunk(Wl[cur ^ 1], Xl[cur ^ 1], tid, wv, xv);
        __syncthreads();
    }

    const int ob = b * 768 + br * 256;
#pragma unroll
    for (int mi = 0; mi < 4; ++mi) {
#pragma unroll
        for (int rI = 0; rI < 4; ++rI) {
            const int d = dbase + wr * 64 + mi * 16 + lg * 4 + rI;
            const float bv = bg[d];
            float m = 0.f;
#pragma unroll
            for (int ni = 0; ni < 4; ++ni) {
                int win = i0 + wc * 64 + ni * 16 + lr;
                float v = acc[mi][ni][rI] + bv;
                v = fmaxf(v, 0.f);
                if (win >= Nw) v = 0.f;
                m = fmaxf(m, v);
            }
#pragma unroll
            for (int off = 1; off < 16; off <<= 1)
                m = fmaxf(m, __shfl_xor(m, off));
            if (lr == 0)
                atomicMax((int*)(out + ob + d), __float_as_int(m));
        }
    }
}

// ---------------- launch ----------------

extern "C" void kernel_launch(void* const* d_in, const int* in_sizes, int n_in,
                              void* d_out, int out_size, void* d_ws, size_t ws_size,
                              hipStream_t stream) {
    const float* x  = (const float*)d_in[0];
    const float* W1 = (const float*)d_in[1];
    const float* W2 = (const float*)d_in[2];
    const float* W3 = (const float*)d_in[3];
    const float* b1 = (const float*)d_in[4];
    const float* b2 = (const float*)d_in[5];
    const float* b3 = (const float*)d_in[6];
    float* out = (float*)d_out;

    hipMemsetAsync(d_out, 0, (size_t)out_size * sizeof(float), stream);

    const size_t need = (size_t)NCHT * 8192 * 2;         // W blob only: ~1.9 MB

    if (ws_size >= need) {
        unsigned short* wbb = (unsigned short*)d_ws;
        pack_w_kernel<<<472, 256, 0, stream>>>(W1, W2, W3, wbb); // 120,832/256 exact
        convgemm_kernel<<<256, 1024, 0, stream>>>(x, wbb, b1, b2, b3, out);
    } else {
        dim3 grid(64, 8, 3);
        convmax_fallback<<<grid, 256, 0, stream>>>(x, W1, W2, W3, b1, b2, b3, out);
    }
}